// Round 1
// baseline (461.975 us; speedup 1.0000x reference)
//
#include <hip/hip_runtime.h>
#include <hip/hip_bf16.h>
#include <cstdio>

typedef __attribute__((ext_vector_type(8))) short short8;
typedef __attribute__((ext_vector_type(4))) float f32x4;
typedef __attribute__((ext_vector_type(4))) unsigned short ushort4v;

__device__ inline unsigned short f2bf(float f){
    unsigned int u = __float_as_uint(f);
    unsigned int r = (u + 0x7fffu + ((u >> 16) & 1u)) >> 16;
    return (unsigned short)r;
}

__device__ inline void store1(float* p, float v){ *p = v; }
__device__ inline void store1(unsigned short* p, float v){ *p = f2bf(v); }

#define BM 128
#define BN 128
#define BK 32

// NT GEMM: C[m,n] = scale*(sum_k A[m,k]*B[n,k]) + epilogue
// A: [M,K] row-major (lda), B: [N,K] row-major (ldb), C: [M,N] (ldc).
// All of M,N multiples of 128; K multiple of 32. Batch via blockIdx.z + strides.
// EPI: 0 = none, 1 = +bias[n], 2 = +bias[m], 3 = +bias[m] + resid[m*ldc+n]
template<typename OutT, int EPI>
__global__ __launch_bounds__(256)
void gemm_nt(const unsigned short* __restrict__ Ag,
             const unsigned short* __restrict__ Bg,
             OutT* __restrict__ Cg,
             int M, int N, int K, int lda, int ldb, int ldc,
             long sA, long sB, long sC,
             const float* __restrict__ bias,
             const float* __restrict__ resid, long sR,
             float scale)
{
    const int bz = blockIdx.z;
    Ag += (long)bz * sA;
    Bg += (long)bz * sB;
    Cg += (long)bz * sC;

    const int m0 = blockIdx.y * BM;
    const int n0 = blockIdx.x * BN;

    __shared__ unsigned short As[BM * BK];
    __shared__ unsigned short Bs[BN * BK];

    const int t    = threadIdx.x;
    const int wave = t >> 6;
    const int lane = t & 63;
    const int wm   = (wave >> 1) << 6;  // wave row offset (0/64)
    const int wn   = (wave & 1) << 6;   // wave col offset (0/64)
    const int lhi  = lane >> 4;         // k-chunk 0..3
    const int llo  = lane & 15;

    f32x4 acc[4][4];
#pragma unroll
    for (int i = 0; i < 4; i++)
#pragma unroll
        for (int j = 0; j < 4; j++) acc[i][j] = (f32x4)(0.0f);

    for (int k0 = 0; k0 < K; k0 += BK){
        __syncthreads();  // previous iter's LDS reads done
        // Stage A and B tiles: rows of 64B (32 bf16), 4 chunks of 16B per row.
        // LDS dest is linear (tt*16 bytes); global source chunk is XOR-swizzled
        // so that swizzled ds_reads below retrieve the right data (rule #21).
#pragma unroll
        for (int i = 0; i < 2; i++){
            const int tt = i * 256 + t;
            const int r  = tt >> 2;
            const int cb = tt & 3;
            const int cs = cb ^ ((r >> 1) & 3);
            const unsigned short* gpA = Ag + (long)(m0 + r) * lda + k0 + cs * 8;
            const unsigned short* gpB = Bg + (long)(n0 + r) * ldb + k0 + cs * 8;
            unsigned short* lpA = As + i * 2048 + wave * 512;  // wave-uniform base
            unsigned short* lpB = Bs + i * 2048 + wave * 512;
            __builtin_amdgcn_global_load_lds(
                (const __attribute__((address_space(1))) void*)gpA,
                (__attribute__((address_space(3))) void*)lpA, 16, 0, 0);
            __builtin_amdgcn_global_load_lds(
                (const __attribute__((address_space(1))) void*)gpB,
                (__attribute__((address_space(3))) void*)lpB, 16, 0, 0);
        }
        __syncthreads();  // compiler drains vmcnt before barrier

        short8 af[4], bf[4];
#pragma unroll
        for (int mi = 0; mi < 4; mi++){
            const int r  = wm + mi * 16 + llo;
            const int cs = lhi ^ ((r >> 1) & 3);
            af[mi] = *(const short8*)(As + r * 32 + cs * 8);
        }
#pragma unroll
        for (int ni = 0; ni < 4; ni++){
            const int r  = wn + ni * 16 + llo;
            const int cs = lhi ^ ((r >> 1) & 3);
            bf[ni] = *(const short8*)(Bs + r * 32 + cs * 8);
        }
#pragma unroll
        for (int mi = 0; mi < 4; mi++)
#pragma unroll
            for (int ni = 0; ni < 4; ni++)
                acc[mi][ni] = __builtin_amdgcn_mfma_f32_16x16x32_bf16(
                    af[mi], bf[ni], acc[mi][ni], 0, 0, 0);
    }

    // Epilogue. D layout: col n = lane&15, row m = (lane>>4)*4 + reg  [m89]
#pragma unroll
    for (int mi = 0; mi < 4; mi++){
#pragma unroll
        for (int ni = 0; ni < 4; ni++){
            const int n  = n0 + wn + ni * 16 + llo;
            const int mb = m0 + wm + mi * 16 + lhi * 4;
            f32x4 v = acc[mi][ni];
#pragma unroll
            for (int j = 0; j < 4; j++){
                const int m = mb + j;
                float val = v[j] * scale;
                if (EPI == 1) val += bias[n];
                if (EPI == 2) val += bias[m];
                if (EPI == 3) val += bias[m] + resid[(long)bz * sR + (long)m * ldc + n];
                store1(&Cg[(long)m * ldc + n], val);
            }
        }
    }
}

// ---- GroupNorm: B=8, C=512, L=2048, G=8 -> 64 (b,g) groups of 131072 elems ----

__global__ void gn_partial(const float* __restrict__ x, float* __restrict__ part){
    const long base = (long)blockIdx.x * 8192;
    const float4* xp = (const float4*)(x + base);
    float s = 0.f, ss = 0.f;
    for (int i = threadIdx.x; i < 2048; i += 256){
        float4 v = xp[i];
        s  += (v.x + v.y) + (v.z + v.w);
        ss += (v.x * v.x + v.y * v.y) + (v.z * v.z + v.w * v.w);
    }
    for (int o = 32; o; o >>= 1){ s += __shfl_down(s, o); ss += __shfl_down(ss, o); }
    __shared__ float rs[4], rss[4];
    const int wave = threadIdx.x >> 6, lane = threadIdx.x & 63;
    if (lane == 0){ rs[wave] = s; rss[wave] = ss; }
    __syncthreads();
    if (threadIdx.x == 0){
        part[blockIdx.x * 2]     = (rs[0] + rs[1]) + (rs[2] + rs[3]);
        part[blockIdx.x * 2 + 1] = (rss[0] + rss[1]) + (rss[2] + rss[3]);
    }
}

__global__ void gn_final(const float* __restrict__ part, float* __restrict__ stats){
    const int bg = threadIdx.x;
    if (bg >= 64) return;
    float s = 0.f, ss = 0.f;
    for (int c = 0; c < 16; c++){
        s  += part[(bg * 16 + c) * 2];
        ss += part[(bg * 16 + c) * 2 + 1];
    }
    const float inv_n = 1.0f / 131072.0f;
    const float mean = s * inv_n;
    const float var  = ss * inv_n - mean * mean;
    stats[bg * 2]     = mean;
    stats[bg * 2 + 1] = rsqrtf(var + 1e-6f);
}

// normalize + affine + transpose: x[b][c][l] fp32 -> h_t[b][l][c] bf16
__global__ void norm_transpose(const float* __restrict__ x, const float* __restrict__ stats,
                               const float* __restrict__ gamma, const float* __restrict__ beta,
                               unsigned short* __restrict__ ht){
    const int b = blockIdx.z, c0 = blockIdx.y * 64, l0 = blockIdx.x * 64;
    const int bg = b * 8 + (c0 >> 6);
    const float mean = stats[bg * 2], rstd = stats[bg * 2 + 1];
    __shared__ unsigned short tile[64][66];  // 66: odd dword stride, no bank conflicts
    const float* xb = x + (long)b * 1048576;
    const int t = threadIdx.x;
#pragma unroll
    for (int i = 0; i < 16; i++){
        const int idx = i * 256 + t;
        const int c = idx >> 6, l = idx & 63;
        float v = xb[(long)(c0 + c) * 2048 + l0 + l];
        v = (v - mean) * rstd * gamma[c0 + c] + beta[c0 + c];
        tile[l][c] = f2bf(v);
    }
    __syncthreads();
    unsigned short* htb = ht + (long)b * 1048576;
#pragma unroll
    for (int i = 0; i < 16; i++){
        const int idx = i * 256 + t;
        const int l = idx >> 6, c = idx & 63;
        htb[(long)(l0 + l) * 512 + c0 + c] = tile[l][c];
    }
}

__global__ void f32_to_bf16(const float4* __restrict__ in, ushort4v* __restrict__ out, int n4){
    const int i = blockIdx.x * 256 + threadIdx.x;
    if (i >= n4) return;
    float4 v = in[i];
    ushort4v o;
    o.x = f2bf(v.x); o.y = f2bf(v.y); o.z = f2bf(v.z); o.w = f2bf(v.w);
    out[i] = o;
}

// row softmax over 2048 fp32 -> bf16
__global__ void softmax_row(const float* __restrict__ s, unsigned short* __restrict__ p){
    const long base = (long)blockIdx.x * 2048;
    const float4* sp = (const float4*)(s + base);
    const int t = threadIdx.x;
    float4 a = sp[t], b = sp[t + 256];
    float mx = fmaxf(fmaxf(fmaxf(a.x, a.y), fmaxf(a.z, a.w)),
                     fmaxf(fmaxf(b.x, b.y), fmaxf(b.z, b.w)));
    for (int o = 32; o; o >>= 1) mx = fmaxf(mx, __shfl_xor(mx, o));
    __shared__ float rmax[4], rsum[4];
    const int wave = t >> 6, lane = t & 63;
    if (lane == 0) rmax[wave] = mx;
    __syncthreads();
    mx = fmaxf(fmaxf(rmax[0], rmax[1]), fmaxf(rmax[2], rmax[3]));
    float e0 = __expf(a.x - mx), e1 = __expf(a.y - mx), e2 = __expf(a.z - mx), e3 = __expf(a.w - mx);
    float e4 = __expf(b.x - mx), e5 = __expf(b.y - mx), e6 = __expf(b.z - mx), e7 = __expf(b.w - mx);
    float sum = ((e0 + e1) + (e2 + e3)) + ((e4 + e5) + (e6 + e7));
    for (int o = 32; o; o >>= 1) sum += __shfl_xor(sum, o);
    if (lane == 0) rsum[wave] = sum;
    __syncthreads();
    sum = (rsum[0] + rsum[1]) + (rsum[2] + rsum[3]);
    const float inv = 1.0f / sum;
    ushort4v o1, o2;
    o1.x = f2bf(e0 * inv); o1.y = f2bf(e1 * inv); o1.z = f2bf(e2 * inv); o1.w = f2bf(e3 * inv);
    o2.x = f2bf(e4 * inv); o2.y = f2bf(e5 * inv); o2.z = f2bf(e6 * inv); o2.w = f2bf(e7 * inv);
    ushort4v* pp = (ushort4v*)(p + base);
    pp[t] = o1; pp[t + 256] = o2;
}

// ---- workspace layout (bytes) ----
enum : long {
    OFF_WQ  = 0,
    OFF_WK  = 524288,
    OFF_WV  = 1048576,
    OFF_WO  = 1572864,
    OFF_HT  = 2097152,              // [B][L][C] bf16, 16.78 MB
    OFF_QT  = OFF_HT  + 16777216,   // [B][L][C] bf16
    OFF_KT  = OFF_QT  + 16777216,   // [B][L][C] bf16
    OFF_V   = OFF_KT  + 16777216,   // [B][C][L] bf16
    OFF_H2  = OFF_V   + 16777216,   // [B][L][C] bf16
    OFF_S   = OFF_H2  + 16777216,   // [L][L] fp32 (per-batch reuse)
    OFF_P   = OFF_S   + 16777216,   // [B][L][L] bf16, 67.1 MB
    OFF_GNP = OFF_P   + 67108864,
    OFF_GNS = OFF_GNP + 8192,
    OFF_END = OFF_GNS + 512
};

extern "C" void kernel_launch(void* const* d_in, const int* in_sizes, int n_in,
                              void* d_out, int out_size, void* d_ws, size_t ws_size,
                              hipStream_t stream)
{
    const float* x     = (const float*)d_in[0];
    const float* gamma = (const float*)d_in[1];
    const float* beta  = (const float*)d_in[2];
    const float* wq    = (const float*)d_in[3];
    const float* bq    = (const float*)d_in[4];
    const float* wk    = (const float*)d_in[5];
    const float* bk    = (const float*)d_in[6];
    const float* wv    = (const float*)d_in[7];
    const float* bv    = (const float*)d_in[8];
    const float* wo    = (const float*)d_in[9];
    const float* bo    = (const float*)d_in[10];
    float* out = (float*)d_out;
    char* ws = (char*)d_ws;

    if (ws_size < (size_t)OFF_END){
        fprintf(stderr, "kernel_launch: ws too small (%zu < %ld)\n", ws_size, (long)OFF_END);
        return;
    }

    unsigned short* WQb = (unsigned short*)(ws + OFF_WQ);
    unsigned short* WKb = (unsigned short*)(ws + OFF_WK);
    unsigned short* WVb = (unsigned short*)(ws + OFF_WV);
    unsigned short* WOb = (unsigned short*)(ws + OFF_WO);
    unsigned short* HT  = (unsigned short*)(ws + OFF_HT);
    unsigned short* QT  = (unsigned short*)(ws + OFF_QT);
    unsigned short* KT  = (unsigned short*)(ws + OFF_KT);
    unsigned short* V   = (unsigned short*)(ws + OFF_V);
    unsigned short* H2  = (unsigned short*)(ws + OFF_H2);
    float*          S   = (float*)(ws + OFF_S);
    unsigned short* P   = (unsigned short*)(ws + OFF_P);
    float*          GNP = (float*)(ws + OFF_GNP);
    float*          GNS = (float*)(ws + OFF_GNS);

    const long LC = 1048576;   // 2048*512 elements
    const long LL = 4194304;   // 2048*2048 elements

    // weights fp32 -> bf16
    f32_to_bf16<<<256, 256, 0, stream>>>((const float4*)wq, (ushort4v*)WQb, 65536);
    f32_to_bf16<<<256, 256, 0, stream>>>((const float4*)wk, (ushort4v*)WKb, 65536);
    f32_to_bf16<<<256, 256, 0, stream>>>((const float4*)wv, (ushort4v*)WVb, 65536);
    f32_to_bf16<<<256, 256, 0, stream>>>((const float4*)wo, (ushort4v*)WOb, 65536);

    // GroupNorm -> h_t [B,L,C] bf16
    gn_partial<<<1024, 256, 0, stream>>>(x, GNP);
    gn_final<<<1, 64, 0, stream>>>(GNP, GNS);
    norm_transpose<<<dim3(32, 8, 8), 256, 0, stream>>>(x, GNS, gamma, beta, HT);

    // q_t[l,o] = sum_c h_t[l,c] wq[o,c] + bq[o]   (M=2048,N=512,K=512)
    gemm_nt<unsigned short, 1><<<dim3(4, 16, 8), 256, 0, stream>>>(
        HT, WQb, QT, 2048, 512, 512, 512, 512, 512, LC, 0, LC, bq, nullptr, 0, 1.0f);
    gemm_nt<unsigned short, 1><<<dim3(4, 16, 8), 256, 0, stream>>>(
        HT, WKb, KT, 2048, 512, 512, 512, 512, 512, LC, 0, LC, bk, nullptr, 0, 1.0f);
    // v[o,l] = sum_c wv[o,c] h_t[l,c] + bv[o]     (M=512,N=2048,K=512)
    gemm_nt<unsigned short, 2><<<dim3(16, 4, 8), 256, 0, stream>>>(
        WVb, HT, V, 512, 2048, 512, 512, 512, 2048, 0, LC, LC, bv, nullptr, 0, 1.0f);

    // scores + softmax per batch (S reused)
    for (int b = 0; b < 8; b++){
        // s[i,j] = sum_c q_t[i,c] k_t[j,c] * C^-0.5  (M=N=2048,K=512)
        gemm_nt<float, 0><<<dim3(16, 16, 1), 256, 0, stream>>>(
            QT + (long)b * LC, KT + (long)b * LC, S,
            2048, 2048, 512, 512, 512, 2048, 0, 0, 0, nullptr, nullptr, 0, 0.04419417382f);
        softmax_row<<<2048, 256, 0, stream>>>(S, P + (long)b * LL);
    }

    // h2_t[i,c] = sum_j p[i,j] v[c,j]             (M=2048,N=512,K=2048)
    gemm_nt<unsigned short, 0><<<dim3(4, 16, 8), 256, 0, stream>>>(
        P, V, H2, 2048, 512, 2048, 2048, 2048, 512, LL, LC, LC, nullptr, nullptr, 0, 1.0f);

    // out[o,l] = sum_c wo[o,c] h2_t[l,c] + bo[o] + x[o,l]  (M=512,N=2048,K=512)
    gemm_nt<float, 3><<<dim3(16, 4, 8), 256, 0, stream>>>(
        WOb, H2, out, 512, 2048, 512, 512, 512, 2048, 0, LC, LC, bo, x, LC, 1.0f);
}

// Round 2
// 309.889 us; speedup vs baseline: 1.4908x; 1.4908x over previous
//
#include <hip/hip_runtime.h>
#include <hip/hip_bf16.h>
#include <cstdio>

typedef __attribute__((ext_vector_type(8))) short short8;
typedef __attribute__((ext_vector_type(8))) unsigned short ushort8;
typedef __attribute__((ext_vector_type(4))) float f32x4;
typedef __attribute__((ext_vector_type(4))) unsigned short ushort4v;

__device__ inline unsigned short f2bf(float f){
    unsigned int u = __float_as_uint(f);
    unsigned int r = (u + 0x7fffu + ((u >> 16) & 1u)) >> 16;
    return (unsigned short)r;
}
__device__ inline float bf2f(unsigned short b){
    return __uint_as_float((unsigned int)b << 16);
}

template<bool NT> __device__ inline void store1(float* p, float v){
    if (NT) __builtin_nontemporal_store(v, p); else *p = v;
}
template<bool NT> __device__ inline void store1(unsigned short* p, float v){
    unsigned short b = f2bf(v);
    if (NT) __builtin_nontemporal_store(b, p); else *p = b;
}

#define BM 128
#define BN 128

// NT GEMM, BK=64: C[m,n] = scale*(sum_k A[m,k]*B[n,k]) + epilogue
// A: [M,K] rm (lda), B: [N,K] rm (ldb). M,N multiples of 128; K mult of 64.
// Grid product must be divisible by 8 (bijective XCD-chunk swizzle inside).
// EPI: 0 none, 1 +bias[n], 2 +bias[m], 3 +bias[m]+resid
template<typename OutT, int EPI, bool NTST>
__global__ __launch_bounds__(256)
void gemm_nt(const unsigned short* __restrict__ Ag,
             const unsigned short* __restrict__ Bg,
             OutT* __restrict__ Cg,
             int K, int lda, int ldb, int ldc,
             long sA, long sB, long sC,
             const float* __restrict__ bias,
             const float* __restrict__ resid, long sR,
             float scale)
{
    // bijective XCD-chunked remap: XCD k gets a contiguous chunk of work ids
    // (for our grids this gives one batch per XCD -> Q/K panels L2-resident)
    const int gx = gridDim.x, gy = gridDim.y;
    const int nwg  = gx * gy * (int)gridDim.z;
    const int orig = blockIdx.x + gx * (blockIdx.y + gy * blockIdx.z);
    const int cpx  = nwg >> 3;
    const int nid  = (orig & 7) * cpx + (orig >> 3);
    const int bx   = nid % gx;
    const int tmp  = nid / gx;
    const int by   = tmp % gy;
    const int bz   = tmp / gy;

    Ag += (long)bz * sA;
    Bg += (long)bz * sB;
    Cg += (long)bz * sC;
    const int m0 = by * BM;
    const int n0 = bx * BN;

    __shared__ unsigned short As[128 * 64];  // 16 KB
    __shared__ unsigned short Bs[128 * 64];  // 16 KB

    const int t    = threadIdx.x;
    const int wave = t >> 6;
    const int lane = t & 63;
    const int wm   = (wave >> 1) << 6;
    const int wn   = (wave & 1) << 6;
    const int lhi  = lane >> 4;   // 16B-chunk selector within K=32 slice
    const int llo  = lane & 15;

    f32x4 acc[4][4];
#pragma unroll
    for (int i = 0; i < 4; i++)
#pragma unroll
        for (int j = 0; j < 4; j++) acc[i][j] = (f32x4)(0.0f);

    for (int k0 = 0; k0 < K; k0 += 64){
        __syncthreads();  // prev iter's LDS reads drained (compiler waits)
        // Stage 128x64 bf16 tiles. Row = 128B = 8 chunks of 16B.
        // LDS dest linear; physical chunk pc=tt&7 holds logical chunk pc^(r&7)
        // -> global source chunk is XOR-swizzled (both-sides rule #21).
#pragma unroll
        for (int i = 0; i < 4; i++){
            const int tt = i * 256 + t;
            const int r  = tt >> 3;
            const int cb = tt & 7;
            const int cs = cb ^ (r & 7);
            const unsigned short* gpA = Ag + (long)(m0 + r) * lda + k0 + cs * 8;
            const unsigned short* gpB = Bg + (long)(n0 + r) * ldb + k0 + cs * 8;
            unsigned short* lpA = As + i * 2048 + wave * 512;  // wave-uniform
            unsigned short* lpB = Bs + i * 2048 + wave * 512;
            __builtin_amdgcn_global_load_lds(
                (const __attribute__((address_space(1))) void*)gpA,
                (__attribute__((address_space(3))) void*)lpA, 16, 0, 0);
            __builtin_amdgcn_global_load_lds(
                (const __attribute__((address_space(1))) void*)gpB,
                (__attribute__((address_space(3))) void*)lpB, 16, 0, 0);
        }
        __syncthreads();

#pragma unroll
        for (int ksub = 0; ksub < 2; ksub++){
            short8 af[4], bf[4];
#pragma unroll
            for (int mi = 0; mi < 4; mi++){
                const int r  = wm + mi * 16 + llo;
                const int cs = (ksub * 4 + lhi) ^ (r & 7);
                af[mi] = *(const short8*)(As + r * 64 + cs * 8);
            }
#pragma unroll
            for (int ni = 0; ni < 4; ni++){
                const int r  = wn + ni * 16 + llo;
                const int cs = (ksub * 4 + lhi) ^ (r & 7);
                bf[ni] = *(const short8*)(Bs + r * 64 + cs * 8);
            }
#pragma unroll
            for (int mi = 0; mi < 4; mi++)
#pragma unroll
                for (int ni = 0; ni < 4; ni++)
                    acc[mi][ni] = __builtin_amdgcn_mfma_f32_16x16x32_bf16(
                        af[mi], bf[ni], acc[mi][ni], 0, 0, 0);
        }
    }

    // D layout: col n = lane&15, row m = (lane>>4)*4 + reg  [m89]
#pragma unroll
    for (int mi = 0; mi < 4; mi++){
#pragma unroll
        for (int ni = 0; ni < 4; ni++){
            const int n  = n0 + wn + ni * 16 + llo;
            const int mb = m0 + wm + mi * 16 + lhi * 4;
            f32x4 v = acc[mi][ni];
#pragma unroll
            for (int j = 0; j < 4; j++){
                const int m = mb + j;
                float val = v[j] * scale;
                if (EPI == 1) val += bias[n];
                if (EPI == 2) val += bias[m];
                if (EPI == 3) val += bias[m] + resid[(long)bz * sR + (long)m * ldc + n];
                store1<NTST>(&Cg[(long)m * ldc + n], val);
            }
        }
    }
}

// ---- GroupNorm: B=8, C=512, L=2048, G=8 -> 64 (b,g) groups ----

__global__ void gn_partial(const float* __restrict__ x, float* __restrict__ part){
    const long base = (long)blockIdx.x * 8192;
    const float4* xp = (const float4*)(x + base);
    float s = 0.f, ss = 0.f;
    for (int i = threadIdx.x; i < 2048; i += 256){
        float4 v = xp[i];
        s  += (v.x + v.y) + (v.z + v.w);
        ss += (v.x * v.x + v.y * v.y) + (v.z * v.z + v.w * v.w);
    }
    for (int o = 32; o; o >>= 1){ s += __shfl_down(s, o); ss += __shfl_down(ss, o); }
    __shared__ float rs[4], rss[4];
    const int wave = threadIdx.x >> 6, lane = threadIdx.x & 63;
    if (lane == 0){ rs[wave] = s; rss[wave] = ss; }
    __syncthreads();
    if (threadIdx.x == 0){
        part[blockIdx.x * 2]     = (rs[0] + rs[1]) + (rs[2] + rs[3]);
        part[blockIdx.x * 2 + 1] = (rss[0] + rss[1]) + (rss[2] + rss[3]);
    }
}

__global__ void gn_final(const float* __restrict__ part, float* __restrict__ stats){
    const int bg = threadIdx.x;
    if (bg >= 64) return;
    float s = 0.f, ss = 0.f;
    for (int c = 0; c < 16; c++){
        s  += part[(bg * 16 + c) * 2];
        ss += part[(bg * 16 + c) * 2 + 1];
    }
    const float inv_n = 1.0f / 131072.0f;
    const float mean = s * inv_n;
    const float var  = ss * inv_n - mean * mean;
    stats[bg * 2]     = mean;
    stats[bg * 2 + 1] = rsqrtf(var + 1e-6f);
}

__global__ void norm_transpose(const float* __restrict__ x, const float* __restrict__ stats,
                               const float* __restrict__ gamma, const float* __restrict__ beta,
                               unsigned short* __restrict__ ht){
    const int b = blockIdx.z, c0 = blockIdx.y * 64, l0 = blockIdx.x * 64;
    const int bg = b * 8 + (c0 >> 6);
    const float mean = stats[bg * 2], rstd = stats[bg * 2 + 1];
    __shared__ unsigned short tile[64][66];
    const float* xb = x + (long)b * 1048576;
    const int t = threadIdx.x;
#pragma unroll
    for (int i = 0; i < 16; i++){
        const int idx = i * 256 + t;
        const int c = idx >> 6, l = idx & 63;
        float v = xb[(long)(c0 + c) * 2048 + l0 + l];
        v = (v - mean) * rstd * gamma[c0 + c] + beta[c0 + c];
        tile[l][c] = f2bf(v);
    }
    __syncthreads();
    unsigned short* htb = ht + (long)b * 1048576;
#pragma unroll
    for (int i = 0; i < 16; i++){
        const int idx = i * 256 + t;
        const int l = idx >> 6, c = idx & 63;
        htb[(long)(l0 + l) * 512 + c0 + c] = tile[l][c];
    }
}

__global__ void f32_to_bf16(const float4* __restrict__ in, ushort4v* __restrict__ out, int n4){
    const int i = blockIdx.x * 256 + threadIdx.x;
    if (i >= n4) return;
    float4 v = in[i];
    ushort4v o;
    o.x = f2bf(v.x); o.y = f2bf(v.y); o.z = f2bf(v.z); o.w = f2bf(v.w);
    out[i] = o;
}

// in-place row softmax over 2048 bf16 (block = row, 256 threads x 8 elems)
__global__ void softmax_inplace(unsigned short* __restrict__ p){
    const long base = (long)blockIdx.x * 2048;
    ushort8* pp = (ushort8*)(p + base);
    const int t = threadIdx.x;
    ushort8 v = pp[t];
    float f[8];
#pragma unroll
    for (int j = 0; j < 8; j++) f[j] = bf2f(v[j]);
    float mx = f[0];
#pragma unroll
    for (int j = 1; j < 8; j++) mx = fmaxf(mx, f[j]);
    for (int o = 32; o; o >>= 1) mx = fmaxf(mx, __shfl_xor(mx, o));
    __shared__ float rmax[4], rsum[4];
    const int wave = t >> 6, lane = t & 63;
    if (lane == 0) rmax[wave] = mx;
    __syncthreads();
    mx = fmaxf(fmaxf(rmax[0], rmax[1]), fmaxf(rmax[2], rmax[3]));
    float sum = 0.f;
#pragma unroll
    for (int j = 0; j < 8; j++){ f[j] = __expf(f[j] - mx); sum += f[j]; }
    for (int o = 32; o; o >>= 1) sum += __shfl_xor(sum, o);
    if (lane == 0) rsum[wave] = sum;
    __syncthreads();
    sum = (rsum[0] + rsum[1]) + (rsum[2] + rsum[3]);
    const float inv = 1.0f / sum;
    ushort8 o8;
#pragma unroll
    for (int j = 0; j < 8; j++) o8[j] = f2bf(f[j] * inv);
    pp[t] = o8;
}

// ---- workspace layout (bytes) ----
enum : long {
    OFF_WQ  = 0,
    OFF_WK  = 524288,
    OFF_WV  = 1048576,
    OFF_WO  = 1572864,
    OFF_HT  = 2097152,              // [B][L][C] bf16
    OFF_QT  = OFF_HT  + 16777216,   // [B][L][C] bf16
    OFF_KT  = OFF_QT  + 16777216,   // [B][L][C] bf16
    OFF_V   = OFF_KT  + 16777216,   // [B][C][L] bf16
    OFF_H2  = OFF_V   + 16777216,   // [B][L][C] bf16
    OFF_P   = OFF_H2  + 16777216,   // [B][L][L] bf16 (S written here, softmax in-place)
    OFF_GNP = OFF_P   + 67108864,
    OFF_GNS = OFF_GNP + 8192,
    OFF_END = OFF_GNS + 512
};

extern "C" void kernel_launch(void* const* d_in, const int* in_sizes, int n_in,
                              void* d_out, int out_size, void* d_ws, size_t ws_size,
                              hipStream_t stream)
{
    const float* x     = (const float*)d_in[0];
    const float* gamma = (const float*)d_in[1];
    const float* beta  = (const float*)d_in[2];
    const float* wq    = (const float*)d_in[3];
    const float* bq    = (const float*)d_in[4];
    const float* wk    = (const float*)d_in[5];
    const float* bk    = (const float*)d_in[6];
    const float* wv    = (const float*)d_in[7];
    const float* bv    = (const float*)d_in[8];
    const float* wo    = (const float*)d_in[9];
    const float* bo    = (const float*)d_in[10];
    float* out = (float*)d_out;
    char* ws = (char*)d_ws;

    if (ws_size < (size_t)OFF_END){
        fprintf(stderr, "kernel_launch: ws too small (%zu < %ld)\n", ws_size, (long)OFF_END);
        return;
    }

    unsigned short* WQb = (unsigned short*)(ws + OFF_WQ);
    unsigned short* WKb = (unsigned short*)(ws + OFF_WK);
    unsigned short* WVb = (unsigned short*)(ws + OFF_WV);
    unsigned short* WOb = (unsigned short*)(ws + OFF_WO);
    unsigned short* HT  = (unsigned short*)(ws + OFF_HT);
    unsigned short* QT  = (unsigned short*)(ws + OFF_QT);
    unsigned short* KT  = (unsigned short*)(ws + OFF_KT);
    unsigned short* V   = (unsigned short*)(ws + OFF_V);
    unsigned short* H2  = (unsigned short*)(ws + OFF_H2);
    unsigned short* P   = (unsigned short*)(ws + OFF_P);
    float*          GNP = (float*)(ws + OFF_GNP);
    float*          GNS = (float*)(ws + OFF_GNS);

    const long LC = 1048576;   // 2048*512
    const long LL = 4194304;   // 2048*2048

    f32_to_bf16<<<256, 256, 0, stream>>>((const float4*)wq, (ushort4v*)WQb, 65536);
    f32_to_bf16<<<256, 256, 0, stream>>>((const float4*)wk, (ushort4v*)WKb, 65536);
    f32_to_bf16<<<256, 256, 0, stream>>>((const float4*)wv, (ushort4v*)WVb, 65536);
    f32_to_bf16<<<256, 256, 0, stream>>>((const float4*)wo, (ushort4v*)WOb, 65536);

    gn_partial<<<1024, 256, 0, stream>>>(x, GNP);
    gn_final<<<1, 64, 0, stream>>>(GNP, GNS);
    norm_transpose<<<dim3(32, 8, 8), 256, 0, stream>>>(x, GNS, gamma, beta, HT);

    // q_t[l,o] / k_t[l,o]  (M=2048,N=512,K=512)
    gemm_nt<unsigned short, 1, false><<<dim3(4, 16, 8), 256, 0, stream>>>(
        HT, WQb, QT, 512, 512, 512, 512, LC, 0, LC, bq, nullptr, 0, 1.0f);
    gemm_nt<unsigned short, 1, false><<<dim3(4, 16, 8), 256, 0, stream>>>(
        HT, WKb, KT, 512, 512, 512, 512, LC, 0, LC, bk, nullptr, 0, 1.0f);
    // v[o,l]  (M=512,N=2048,K=512)
    gemm_nt<unsigned short, 2, false><<<dim3(16, 4, 8), 256, 0, stream>>>(
        WVb, HT, V, 512, 512, 512, 2048, 0, LC, LC, bv, nullptr, 0, 1.0f);

    // scores -> P bf16, all batches, one launch (NT stores; batch-per-XCD)
    gemm_nt<unsigned short, 0, true><<<dim3(16, 16, 8), 256, 0, stream>>>(
        QT, KT, P, 512, 512, 512, 2048, LC, LC, LL, nullptr, nullptr, 0, 0.04419417382f);

    // softmax in-place on P
    softmax_inplace<<<16384, 256, 0, stream>>>(P);

    // h2_t[i,c] = sum_j p[i,j] v[c,j]  (M=2048,N=512,K=2048)
    gemm_nt<unsigned short, 0, false><<<dim3(4, 16, 8), 256, 0, stream>>>(
        P, V, H2, 2048, 2048, 2048, 512, LL, LC, LC, nullptr, nullptr, 0, 1.0f);

    // out[o,l] = sum_c wo[o,c] h2_t[l,c] + bo[o] + x[o,l]  (M=512,N=2048,K=512)
    gemm_nt<float, 3, false><<<dim3(16, 4, 8), 256, 0, stream>>>(
        WOb, H2, out, 512, 512, 512, 2048, 0, LC, LC, bo, x, LC, 1.0f);
}

// Round 3
// 285.771 us; speedup vs baseline: 1.6166x; 1.0844x over previous
//
#include <hip/hip_runtime.h>
#include <hip/hip_bf16.h>
#include <cstdio>

typedef __attribute__((ext_vector_type(8))) short short8;
typedef __attribute__((ext_vector_type(8))) unsigned short ushort8;
typedef __attribute__((ext_vector_type(4))) float f32x4;
typedef __attribute__((ext_vector_type(4))) unsigned short ushort4v;

__device__ inline unsigned short f2bf(float f){
    unsigned int u = __float_as_uint(f);
    unsigned int r = (u + 0x7fffu + ((u >> 16) & 1u)) >> 16;
    return (unsigned short)r;
}
__device__ inline float bf2f(unsigned short b){
    return __uint_as_float((unsigned int)b << 16);
}

__device__ inline void store1(float* p, float v){ *p = v; }
__device__ inline void store1(unsigned short* p, float v){ *p = f2bf(v); }

#define BM 128
#define BN 128

// NT GEMM, BK=64, double-buffered 2-phase pipeline.
// C[m,n] = scale*(sum_k A[m,k]*B[n,k]) + epilogue
// A: [M,K] rm (lda), B: [N,K] rm (ldb). M,N multiples of 128; K mult of 64.
// Grid product must be divisible by 8 (bijective XCD-chunk swizzle inside;
// for our grids the z (batch) dim lands one batch per XCD).
// EPI: 0 none, 1 +bias[n], 2 +bias[m], 3 +bias[m]+resid
template<typename OutT, int EPI>
__global__ __launch_bounds__(256)
void gemm_nt(const unsigned short* __restrict__ Ag,
             const unsigned short* __restrict__ Bg,
             OutT* __restrict__ Cg,
             int K, int lda, int ldb, int ldc,
             long sA, long sB, long sC,
             const float* __restrict__ bias,
             const float* __restrict__ resid, long sR,
             float scale)
{
    const int gx = gridDim.x, gy = gridDim.y;
    const int nwg  = gx * gy * (int)gridDim.z;
    const int orig = blockIdx.x + gx * (blockIdx.y + gy * blockIdx.z);
    const int cpx  = nwg >> 3;
    const int nid  = (orig & 7) * cpx + (orig >> 3);
    const int bx   = nid % gx;
    const int tmp  = nid / gx;
    const int by   = tmp % gy;
    const int bz   = tmp / gy;

    Ag += (long)bz * sA;
    Bg += (long)bz * sB;
    Cg += (long)bz * sC;
    const int m0 = by * BM;
    const int n0 = bx * BN;

    __shared__ unsigned short As[2][128 * 64];  // 2 x 16 KB
    __shared__ unsigned short Bs[2][128 * 64];  // 2 x 16 KB  (total 64 KB)

    const int t    = threadIdx.x;
    const int wave = t >> 6;
    const int lane = t & 63;
    const int wm   = (wave >> 1) << 6;
    const int wn   = (wave & 1) << 6;
    const int lhi  = lane >> 4;
    const int llo  = lane & 15;

    f32x4 acc[4][4];
#pragma unroll
    for (int i = 0; i < 4; i++)
#pragma unroll
        for (int j = 0; j < 4; j++) acc[i][j] = (f32x4)(0.0f);

    // Stage 128x64 bf16 tiles. Row = 128B = 8 chunks of 16B. LDS dest linear;
    // physical chunk pc holds logical chunk pc^(r&7): global source chunk is
    // XOR-swizzled, ds_reads below apply the same XOR (both-sides rule #21).
    auto stage = [&](int bi, int k0){
#pragma unroll
        for (int i = 0; i < 4; i++){
            const int tt = i * 256 + t;
            const int r  = tt >> 3;
            const int cb = tt & 7;
            const int cs = cb ^ (r & 7);
            const unsigned short* gpA = Ag + (long)(m0 + r) * lda + k0 + cs * 8;
            const unsigned short* gpB = Bg + (long)(n0 + r) * ldb + k0 + cs * 8;
            unsigned short* lpA = &As[bi][i * 2048 + wave * 512];  // wave-uniform
            unsigned short* lpB = &Bs[bi][i * 2048 + wave * 512];
            __builtin_amdgcn_global_load_lds(
                (const __attribute__((address_space(1))) void*)gpA,
                (__attribute__((address_space(3))) void*)lpA, 16, 0, 0);
            __builtin_amdgcn_global_load_lds(
                (const __attribute__((address_space(1))) void*)gpB,
                (__attribute__((address_space(3))) void*)lpB, 16, 0, 0);
        }
    };

    const int nt = K >> 6;
    stage(0, 0);
    __syncthreads();   // prologue loads complete (compiler drains vmcnt)

    int cur = 0;
    for (int kt = 0; kt < nt; kt++){
        if (kt + 1 < nt) stage(cur ^ 1, (kt + 1) << 6);  // prefetch next tile
#pragma unroll
        for (int ksub = 0; ksub < 2; ksub++){
            short8 af[4], bf[4];
#pragma unroll
            for (int mi = 0; mi < 4; mi++){
                const int r  = wm + mi * 16 + llo;
                const int cs = (ksub * 4 + lhi) ^ (r & 7);
                af[mi] = *(const short8*)(&As[cur][r * 64 + cs * 8]);
            }
#pragma unroll
            for (int ni = 0; ni < 4; ni++){
                const int r  = wn + ni * 16 + llo;
                const int cs = (ksub * 4 + lhi) ^ (r & 7);
                bf[ni] = *(const short8*)(&Bs[cur][r * 64 + cs * 8]);
            }
#pragma unroll
            for (int mi = 0; mi < 4; mi++)
#pragma unroll
                for (int ni = 0; ni < 4; ni++)
                    acc[mi][ni] = __builtin_amdgcn_mfma_f32_16x16x32_bf16(
                        af[mi], bf[ni], acc[mi][ni], 0, 0, 0);
        }
        __syncthreads();  // next-tile loads done; cur fully consumed
        cur ^= 1;
    }

    // D layout: col n = lane&15, row m = (lane>>4)*4 + reg  [m89]
#pragma unroll
    for (int mi = 0; mi < 4; mi++){
#pragma unroll
        for (int ni = 0; ni < 4; ni++){
            const int n  = n0 + wn + ni * 16 + llo;
            const int mb = m0 + wm + mi * 16 + lhi * 4;
            f32x4 v = acc[mi][ni];
#pragma unroll
            for (int j = 0; j < 4; j++){
                const int m = mb + j;
                float val = v[j] * scale;
                if (EPI == 1) val += bias[n];
                if (EPI == 2) val += bias[m];
                if (EPI == 3) val += bias[m] + resid[(long)bz * sR + (long)m * ldc + n];
                store1(&Cg[(long)m * ldc + n], val);
            }
        }
    }
}

// ---- GroupNorm: B=8, C=512, L=2048, G=8 -> 64 (b,g) groups ----

__global__ void gn_partial(const float* __restrict__ x, float* __restrict__ part){
    const long base = (long)blockIdx.x * 8192;
    const float4* xp = (const float4*)(x + base);
    float s = 0.f, ss = 0.f;
    for (int i = threadIdx.x; i < 2048; i += 256){
        float4 v = xp[i];
        s  += (v.x + v.y) + (v.z + v.w);
        ss += (v.x * v.x + v.y * v.y) + (v.z * v.z + v.w * v.w);
    }
    for (int o = 32; o; o >>= 1){ s += __shfl_down(s, o); ss += __shfl_down(ss, o); }
    __shared__ float rs[4], rss[4];
    const int wave = threadIdx.x >> 6, lane = threadIdx.x & 63;
    if (lane == 0){ rs[wave] = s; rss[wave] = ss; }
    __syncthreads();
    if (threadIdx.x == 0){
        part[blockIdx.x * 2]     = (rs[0] + rs[1]) + (rs[2] + rs[3]);
        part[blockIdx.x * 2 + 1] = (rss[0] + rss[1]) + (rss[2] + rss[3]);
    }
}

__global__ void gn_final(const float* __restrict__ part, float* __restrict__ stats){
    const int bg = threadIdx.x;
    if (bg >= 64) return;
    float s = 0.f, ss = 0.f;
    for (int c = 0; c < 16; c++){
        s  += part[(bg * 16 + c) * 2];
        ss += part[(bg * 16 + c) * 2 + 1];
    }
    const float inv_n = 1.0f / 131072.0f;
    const float mean = s * inv_n;
    const float var  = ss * inv_n - mean * mean;
    stats[bg * 2]     = mean;
    stats[bg * 2 + 1] = rsqrtf(var + 1e-6f);
}

__global__ void norm_transpose(const float* __restrict__ x, const float* __restrict__ stats,
                               const float* __restrict__ gamma, const float* __restrict__ beta,
                               unsigned short* __restrict__ ht){
    const int b = blockIdx.z, c0 = blockIdx.y * 64, l0 = blockIdx.x * 64;
    const int bg = b * 8 + (c0 >> 6);
    const float mean = stats[bg * 2], rstd = stats[bg * 2 + 1];
    __shared__ unsigned short tile[64][66];
    const float* xb = x + (long)b * 1048576;
    const int t = threadIdx.x;
#pragma unroll
    for (int i = 0; i < 16; i++){
        const int idx = i * 256 + t;
        const int c = idx >> 6, l = idx & 63;
        float v = xb[(long)(c0 + c) * 2048 + l0 + l];
        v = (v - mean) * rstd * gamma[c0 + c] + beta[c0 + c];
        tile[l][c] = f2bf(v);
    }
    __syncthreads();
    unsigned short* htb = ht + (long)b * 1048576;
#pragma unroll
    for (int i = 0; i < 16; i++){
        const int idx = i * 256 + t;
        const int l = idx >> 6, c = idx & 63;
        htb[(long)(l0 + l) * 512 + c0 + c] = tile[l][c];
    }
}

// all four [512,512] f32 weights -> bf16 into contiguous ws region
__global__ void weights_to_bf16(const float4* __restrict__ wq, const float4* __restrict__ wk,
                                const float4* __restrict__ wv, const float4* __restrict__ wo,
                                ushort4v* __restrict__ out){
    const int i = blockIdx.x * 256 + threadIdx.x;     // 0 .. 262143
    const int w = i >> 16, off = i & 65535;
    const float4* src = (w == 0) ? wq : (w == 1) ? wk : (w == 2) ? wv : wo;
    float4 v = src[off];
    ushort4v o;
    o.x = f2bf(v.x); o.y = f2bf(v.y); o.z = f2bf(v.z); o.w = f2bf(v.w);
    out[i] = o;
}

// in-place row softmax over 2048 bf16 (block = row)
__global__ void softmax_inplace(unsigned short* __restrict__ p){
    const long base = (long)blockIdx.x * 2048;
    ushort8* pp = (ushort8*)(p + base);
    const int t = threadIdx.x;
    ushort8 v = pp[t];
    float f[8];
#pragma unroll
    for (int j = 0; j < 8; j++) f[j] = bf2f(v[j]);
    float mx = f[0];
#pragma unroll
    for (int j = 1; j < 8; j++) mx = fmaxf(mx, f[j]);
    for (int o = 32; o; o >>= 1) mx = fmaxf(mx, __shfl_xor(mx, o));
    __shared__ float rmax[4], rsum[4];
    const int wave = t >> 6, lane = t & 63;
    if (lane == 0) rmax[wave] = mx;
    __syncthreads();
    mx = fmaxf(fmaxf(rmax[0], rmax[1]), fmaxf(rmax[2], rmax[3]));
    float sum = 0.f;
#pragma unroll
    for (int j = 0; j < 8; j++){ f[j] = __expf(f[j] - mx); sum += f[j]; }
    for (int o = 32; o; o >>= 1) sum += __shfl_xor(sum, o);
    if (lane == 0) rsum[wave] = sum;
    __syncthreads();
    sum = (rsum[0] + rsum[1]) + (rsum[2] + rsum[3]);
    const float inv = 1.0f / sum;
    ushort8 o8;
#pragma unroll
    for (int j = 0; j < 8; j++) o8[j] = f2bf(f[j] * inv);
    pp[t] = o8;
}

// ---- workspace layout (bytes) ----
enum : long {
    OFF_WQ  = 0,
    OFF_WK  = 524288,
    OFF_WV  = 1048576,
    OFF_WO  = 1572864,
    OFF_HT  = 2097152,              // [B][L][C] bf16
    OFF_QT  = OFF_HT  + 16777216,   // [B][L][C] bf16
    OFF_KT  = OFF_QT  + 16777216,   // [B][L][C] bf16
    OFF_V   = OFF_KT  + 16777216,   // [B][C][L] bf16
    OFF_H2  = OFF_V   + 16777216,   // [B][L][C] bf16
    OFF_P   = OFF_H2  + 16777216,   // [B][L][L] bf16 (S written here, softmax in-place)
    OFF_GNP = OFF_P   + 67108864,
    OFF_GNS = OFF_GNP + 8192,
    OFF_END = OFF_GNS + 512
};

extern "C" void kernel_launch(void* const* d_in, const int* in_sizes, int n_in,
                              void* d_out, int out_size, void* d_ws, size_t ws_size,
                              hipStream_t stream)
{
    const float* x     = (const float*)d_in[0];
    const float* gamma = (const float*)d_in[1];
    const float* beta  = (const float*)d_in[2];
    const float* wq    = (const float*)d_in[3];
    const float* bq    = (const float*)d_in[4];
    const float* wk    = (const float*)d_in[5];
    const float* bk    = (const float*)d_in[6];
    const float* wv    = (const float*)d_in[7];
    const float* bv    = (const float*)d_in[8];
    const float* wo    = (const float*)d_in[9];
    const float* bo    = (const float*)d_in[10];
    float* out = (float*)d_out;
    char* ws = (char*)d_ws;

    if (ws_size < (size_t)OFF_END){
        fprintf(stderr, "kernel_launch: ws too small (%zu < %ld)\n", ws_size, (long)OFF_END);
        return;
    }

    unsigned short* HT  = (unsigned short*)(ws + OFF_HT);
    unsigned short* QT  = (unsigned short*)(ws + OFF_QT);
    unsigned short* KT  = (unsigned short*)(ws + OFF_KT);
    unsigned short* V   = (unsigned short*)(ws + OFF_V);
    unsigned short* H2  = (unsigned short*)(ws + OFF_H2);
    unsigned short* P   = (unsigned short*)(ws + OFF_P);
    float*          GNP = (float*)(ws + OFF_GNP);
    float*          GNS = (float*)(ws + OFF_GNS);
    unsigned short* WQb = (unsigned short*)(ws + OFF_WQ);
    unsigned short* WKb = (unsigned short*)(ws + OFF_WK);
    unsigned short* WVb = (unsigned short*)(ws + OFF_WV);
    unsigned short* WOb = (unsigned short*)(ws + OFF_WO);

    const long LC = 1048576;   // 2048*512
    const long LL = 4194304;   // 2048*2048

    weights_to_bf16<<<1024, 256, 0, stream>>>(
        (const float4*)wq, (const float4*)wk, (const float4*)wv, (const float4*)wo,
        (ushort4v*)(ws + OFF_WQ));

    gn_partial<<<1024, 256, 0, stream>>>(x, GNP);
    gn_final<<<1, 64, 0, stream>>>(GNP, GNS);
    norm_transpose<<<dim3(32, 8, 8), 256, 0, stream>>>(x, GNS, gamma, beta, HT);

    // q_t[l,o] / k_t[l,o]  (M=2048,N=512,K=512)
    gemm_nt<unsigned short, 1><<<dim3(4, 16, 8), 256, 0, stream>>>(
        HT, WQb, QT, 512, 512, 512, 512, LC, 0, LC, bq, nullptr, 0, 1.0f);
    gemm_nt<unsigned short, 1><<<dim3(4, 16, 8), 256, 0, stream>>>(
        HT, WKb, KT, 512, 512, 512, 512, LC, 0, LC, bk, nullptr, 0, 1.0f);
    // v[o,l]  (M=512,N=2048,K=512)
    gemm_nt<unsigned short, 2><<<dim3(16, 4, 8), 256, 0, stream>>>(
        WVb, HT, V, 512, 512, 512, 2048, 0, LC, LC, bv, nullptr, 0, 1.0f);

    // scores -> P bf16, all batches, one launch (batch-per-XCD)
    gemm_nt<unsigned short, 0><<<dim3(16, 16, 8), 256, 0, stream>>>(
        QT, KT, P, 512, 512, 512, 2048, LC, LC, LL, nullptr, nullptr, 0, 0.04419417382f);

    // softmax in-place on P
    softmax_inplace<<<16384, 256, 0, stream>>>(P);

    // h2_t[i,c] = sum_j p[i,j] v[c,j]  (M=2048,N=512,K=2048)
    gemm_nt<unsigned short, 0><<<dim3(4, 16, 8), 256, 0, stream>>>(
        P, V, H2, 2048, 2048, 2048, 512, LL, LC, LC, nullptr, nullptr, 0, 1.0f);

    // out[o,l] = sum_c wo[o,c] h2_t[l,c] + bo[o] + x[o,l]  (M=512,N=2048,K=512)
    gemm_nt<float, 3><<<dim3(16, 4, 8), 256, 0, stream>>>(
        WOb, H2, out, 512, 512, 512, 2048, 0, LC, LC, bo, x, LC, 1.0f);
}